// Round 2
// baseline (475.807 us; speedup 1.0000x reference)
//
#include <hip/hip_runtime.h>
#include <math.h>

// Problem constants
#define B_ 8
#define L_ 8
#define DK 256
#define DV 128
#define HS 48
#define WS_ 64
#define HW 3072            // HS*WS
#define QSTRIDE 786432     // DK*HW (one batch of q/knew/fc slot)
#define VSTRIDE 393216     // DV*HW

// ---------------- GEMM: C[b][e][p] = sum_d W[d][e] * X[b][d][p] ----------------
// fp32 tiled: block tile 64(e) x 128(p), 256 threads, thread tile 4x8, K-step 16.
#define KS 16
#define BE 64
#define BP 128

#define FMA4(acc, s, v) { acc.x += (s)*(v).x; acc.y += (s)*(v).y; acc.z += (s)*(v).z; acc.w += (s)*(v).w; }

__global__ __launch_bounds__(256) void gemm_tn(const float* __restrict__ W,
                                               const float* __restrict__ X,
                                               float* __restrict__ C,
                                               int D, int E) {
    const int P = HW;
    const int bp = blockIdx.x * BP;
    const int be = blockIdx.y * BE;
    const int b  = blockIdx.z;
    X += (size_t)b * D * P;
    C += (size_t)b * E * P;

    __shared__ float Ws[KS][BE];
    __shared__ float Xs[KS][BP];

    const int tid = threadIdx.x;
    const int tx = tid & 15;   // pixel group: pixels bp + tx*8 .. +7
    const int ty = tid >> 4;   // e group: e = be + ty*4 .. +3

    float4 acc0[4] = {};
    float4 acc1[4] = {};

    for (int d0 = 0; d0 < D; d0 += KS) {
        __syncthreads();
        // stage W tile: 16 rows x 64 cols = 256 float4, 1 per thread
        {
            int row = tid >> 4, col = tid & 15;
            *(float4*)&Ws[row][col * 4] =
                *(const float4*)&W[(size_t)(d0 + row) * E + be + col * 4];
        }
        // stage X tile: 16 rows x 128 cols = 512 float4, 2 per thread
        {
            int f = tid;
            int row = f >> 5, col = f & 31;
            *(float4*)&Xs[row][col * 4] =
                *(const float4*)&X[(size_t)(d0 + row) * P + bp + col * 4];
            f = tid + 256; row = f >> 5; col = f & 31;
            *(float4*)&Xs[row][col * 4] =
                *(const float4*)&X[(size_t)(d0 + row) * P + bp + col * 4];
        }
        __syncthreads();
        #pragma unroll
        for (int k = 0; k < KS; ++k) {
            float4 a  = *(float4*)&Ws[k][ty * 4];
            float4 b0 = *(float4*)&Xs[k][tx * 8];
            float4 b1 = *(float4*)&Xs[k][tx * 8 + 4];
            FMA4(acc0[0], a.x, b0); FMA4(acc1[0], a.x, b1);
            FMA4(acc0[1], a.y, b0); FMA4(acc1[1], a.y, b1);
            FMA4(acc0[2], a.z, b0); FMA4(acc1[2], a.z, b1);
            FMA4(acc0[3], a.w, b0); FMA4(acc1[3], a.w, b1);
        }
    }
    #pragma unroll
    for (int i = 0; i < 4; ++i) {
        int e = be + ty * 4 + i;
        *(float4*)&C[(size_t)e * P + bp + tx * 8]     = acc0[i];
        *(float4*)&C[(size_t)e * P + bp + tx * 8 + 4] = acc1[i];
    }
}

// ---------------- Scores + softmax (over width axis, faithful to reference) ----
// One wave per (b, l, h) row of 64 pixels. lane = p4(0..15) + 16*dq(0..3).
// score[l][p] = scale * sum_d q[b,d,h,p] * kb[b,l,d,h,p], kb[l<7]=key_buffer[b,l+1], kb[7]=knew.
__global__ __launch_bounds__(64) void scores_kernel(const float* __restrict__ q,
                                                    const float* __restrict__ knew,
                                                    const float* __restrict__ key_buffer,
                                                    float* __restrict__ attn,
                                                    float scale) {
    const int bx = blockIdx.x;           // b*L_*HS + l*HS + h
    const int b = bx / (L_ * HS);
    const int rem = bx % (L_ * HS);
    const int l = rem / HS;
    const int h = rem % HS;

    const int lane = threadIdx.x;
    const int p4 = lane & 15;            // pixels 4*p4 .. +3
    const int dq = lane >> 4;            // d range [dq*64, dq*64+64)

    const float* qbase = q + (size_t)b * QSTRIDE + h * WS_;
    const float* kbase = (l < 7)
        ? key_buffer + (size_t)(b * L_ + l + 1) * QSTRIDE + h * WS_
        : knew + (size_t)b * QSTRIDE + h * WS_;

    const float* kp = kbase + (size_t)(dq * 64) * HW + p4 * 4;
    const float* qp = qbase + (size_t)(dq * 64) * HW + p4 * 4;

    float4 s = {0.f, 0.f, 0.f, 0.f};
    #pragma unroll 8
    for (int d = 0; d < 64; ++d) {
        float4 kv = *(const float4*)kp; kp += HW;
        float4 qv = *(const float4*)qp; qp += HW;
        s.x += qv.x * kv.x; s.y += qv.y * kv.y;
        s.z += qv.z * kv.z; s.w += qv.w * kv.w;
    }
    // reduce over the 4 d-quarters (lane bits 4,5)
    #pragma unroll
    for (int off = 16; off <= 32; off <<= 1) {
        s.x += __shfl_xor(s.x, off);
        s.y += __shfl_xor(s.y, off);
        s.z += __shfl_xor(s.z, off);
        s.w += __shfl_xor(s.w, off);
    }
    s.x *= scale; s.y *= scale; s.z *= scale; s.w *= scale;

    // softmax over the 64 pixels of this (b,l,h) row (distributed 4/lane over 16 lanes)
    float m = fmaxf(fmaxf(s.x, s.y), fmaxf(s.z, s.w));
    #pragma unroll
    for (int off = 1; off <= 8; off <<= 1) m = fmaxf(m, __shfl_xor(m, off));
    float4 e;
    e.x = __expf(s.x - m); e.y = __expf(s.y - m);
    e.z = __expf(s.z - m); e.w = __expf(s.w - m);
    float sum = e.x + e.y + e.z + e.w;
    #pragma unroll
    for (int off = 1; off <= 8; off <<= 1) sum += __shfl_xor(sum, off);
    float inv = 1.0f / sum;
    e.x *= inv; e.y *= inv; e.z *= inv; e.w *= inv;

    if (dq == 0) {
        *(float4*)&attn[(size_t)((b * L_ + l) * HS + h) * WS_ + p4 * 4] = e;
    }
}

// ---------------- PV + epilogue: out[b,e,h,w] = fm + sum_l attn[l]*vb[l,e] -----
// 768 blocks: (b, h, e-half). 256 threads: p4 = tid&15 (4 pixels), eg = tid>>4 (4 e's).
__global__ __launch_bounds__(256) void pv_kernel(const float* __restrict__ attn,
                                                 const float* __restrict__ value_buffer,
                                                 const float* __restrict__ vnew,
                                                 const float* __restrict__ fm,
                                                 float* __restrict__ out) {
    const int bx = blockIdx.x;           // b*96 + h*2 + eh
    const int b = bx / 96;
    const int rem = bx % 96;
    const int h = rem >> 1;
    const int eh = rem & 1;

    const int tid = threadIdx.x;
    const int p4 = tid & 15;
    const int eg = tid >> 4;
    const int e0 = eh * 64 + eg * 4;

    // attention weights for my 4 pixels, all 8 slots
    float4 ar[8];
    #pragma unroll
    for (int l = 0; l < 8; ++l)
        ar[l] = *(const float4*)&attn[(size_t)((b * L_ + l) * HS + h) * WS_ + p4 * 4];

    const float* vb[8];
    #pragma unroll
    for (int l = 0; l < 7; ++l)
        vb[l] = value_buffer + (size_t)(b * L_ + l + 1) * VSTRIDE + h * WS_;
    vb[7] = vnew + (size_t)b * VSTRIDE + h * WS_;

    const float* fmb = fm + (size_t)b * VSTRIDE + h * WS_;
    float* outb = out + (size_t)b * VSTRIDE + h * WS_;

    #pragma unroll
    for (int i = 0; i < 4; ++i) {
        const int e = e0 + i;
        const size_t off = (size_t)e * HW + p4 * 4;
        float4 acc = {0.f, 0.f, 0.f, 0.f};
        #pragma unroll
        for (int l = 0; l < 8; ++l) {
            float4 v = *(const float4*)(vb[l] + off);
            acc.x += ar[l].x * v.x; acc.y += ar[l].y * v.y;
            acc.z += ar[l].z * v.z; acc.w += ar[l].w * v.w;
        }
        float4 f = *(const float4*)(fmb + off);
        f.x += acc.x; f.y += acc.y; f.z += acc.z; f.w += acc.w;
        *(float4*)(outb + off) = f;
    }
}

// ---------------- launcher ----------------------------------------------------
extern "C" void kernel_launch(void* const* d_in, const int* in_sizes, int n_in,
                              void* d_out, int out_size, void* d_ws, size_t ws_size,
                              hipStream_t stream) {
    const float* fc           = (const float*)d_in[0];
    const float* fm           = (const float*)d_in[1];
    const float* key_buffer   = (const float*)d_in[2];
    const float* value_buffer = (const float*)d_in[3];
    const float* Q            = (const float*)d_in[4];
    const float* K            = (const float*)d_in[5];
    const float* V            = (const float*)d_in[6];
    float* out = (float*)d_out;

    float* ws   = (float*)d_ws;
    float* q    = ws;                       // 8*256*3072 = 6291456 floats
    float* knew = ws + 6291456;             // 6291456 floats
    float* vnew = ws + 12582912;            // 8*128*3072 = 3145728 floats
    float* attn = ws + 15728640;            // 8*8*48*64  = 196608 floats

    // scale = log(L*Hs*Ws + Hs*Ws) / log(1000) / sqrt(Dk)
    const float scale = (float)(log(27648.0) / log(1000.0) / 16.0);

    // q = fc @ Q, knew = fc @ K   (D=E=256) — scores deps first
    gemm_tn<<<dim3(HW / BP, DK / BE, B_), 256, 0, stream>>>(Q, fc, q, DK, DK);
    gemm_tn<<<dim3(HW / BP, DK / BE, B_), 256, 0, stream>>>(K, fc, knew, DK, DK);
    // vnew = fm @ V   (D=E=128)
    gemm_tn<<<dim3(HW / BP, DV / BE, B_), 256, 0, stream>>>(V, fm, vnew, DV, DV);

    // scores + softmax over width
    scores_kernel<<<B_ * L_ * HS, 64, 0, stream>>>(q, knew, key_buffer, attn, scale);

    // PV + residual epilogue
    pv_kernel<<<B_ * HS * 2, 256, 0, stream>>>(attn, value_buffer, vnew, fm, out);
}

// Round 3
// 426.788 us; speedup vs baseline: 1.1149x; 1.1149x over previous
//
#include <hip/hip_runtime.h>
#include <hip/hip_bf16.h>
#include <math.h>

// Problem constants
#define B_ 8
#define L_ 8
#define DK 256
#define DV 128
#define HS 48
#define WS_ 64
#define HW 3072            // HS*WS
#define QSTRIDE 786432     // DK*HW
#define VSTRIDE 393216     // DV*HW

typedef unsigned short ushort_t;
typedef __attribute__((ext_vector_type(8))) short short8v;   // 8 bf16 = 4 VGPR
typedef __attribute__((ext_vector_type(4))) float float4v;   // MFMA C/D

// ---------------- prep: W[d][e] fp32 -> Wt_hi/lo[e][d] bf16 --------------------
// hi = bf16(x), lo = bf16(x - hi). 640 blocks (256 Q + 256 K + 128 V), 256 thr.
__global__ __launch_bounds__(256) void prep_weights(
    const float* __restrict__ Q, const float* __restrict__ K, const float* __restrict__ V,
    ushort_t* __restrict__ WQh, ushort_t* __restrict__ WQl,
    ushort_t* __restrict__ WKh, ushort_t* __restrict__ WKl,
    ushort_t* __restrict__ WVh, ushort_t* __restrict__ WVl) {
    const int bid = blockIdx.x;
    const float* W; ushort_t *Wh, *Wl; int D, e;
    if (bid < 256)      { W = Q; Wh = WQh; Wl = WQl; D = 256; e = bid; }
    else if (bid < 512) { W = K; Wh = WKh; Wl = WKl; D = 256; e = bid - 256; }
    else                { W = V; Wh = WVh; Wl = WVl; D = 128; e = bid - 512; }
    const int d = threadIdx.x;
    if (d < D) {
        float x = W[(size_t)d * D + e];
        __hip_bfloat16 h = __float2bfloat16(x);
        float hf = __bfloat162float(h);
        __hip_bfloat16 lo = __float2bfloat16(x - hf);
        Wh[(size_t)e * D + d] = *(ushort_t*)&h;
        Wl[(size_t)e * D + d] = *(ushort_t*)&lo;
    }
}

// ---------------- MFMA GEMM: C[b][e][p] = sum_d W[d][e] * X[b][d][p] ----------
// Split bf16: acc += Ah*Bh + Ah*Bl + Al*Bh. Block tile 64e x 64p, 4 waves,
// wave w owns e-strip [be+16w, +16), 4 p-frags. K staged in LDS 32 at a time.
// A frag (W): lane e = estrip + (lane&15), k = k0 + (lane>>4)*8 + j  (global, L2)
// B frag (X): lane p = pf*16 + (lane&15), k = same                   (LDS)
// C frag:     p = pf*16 + (lane&15), e = estrip + (lane>>4)*4 + i    (m89 layout)
template<int NW, int D>
__global__ __launch_bounds__(256) void gemm_mfma(
    const float* __restrict__ X,
    const ushort_t* __restrict__ W1h, const ushort_t* __restrict__ W1l,
    const ushort_t* __restrict__ W2h, const ushort_t* __restrict__ W2l,
    float* __restrict__ C1, float* __restrict__ C2) {
    const int bp = blockIdx.x * 64;
    const int be = blockIdx.y * 64;
    const int b  = blockIdx.z;
    X  += (size_t)b * D * HW;

    __shared__ ushort_t Xh[64][40];   // [p][k], 32 k used, pad->40 (80B rows)
    __shared__ ushort_t Xl[64][40];

    const int tid  = threadIdx.x;
    const int lane = tid & 63;
    const int w    = tid >> 6;
    const int l15  = lane & 15;
    const int kg   = (lane >> 4) * 8;

    float4v acc1[4] = {};
    float4v acc2[4] = {};

    const int estrip = be + w * 16;
    const size_t arow = (size_t)(estrip + l15) * D;

    for (int k0 = 0; k0 < D; k0 += 32) {
        __syncthreads();
        // stage X chunk [32k][64p] fp32 -> bf16 hi/lo LDS [64p][32k]
        #pragma unroll
        for (int r = 0; r < 2; ++r) {
            int v  = tid + 256 * r;        // 0..511 float4s
            int kk = v >> 4;               // 0..31
            int p4 = (v & 15) * 4;
            float4 g = *(const float4*)&X[(size_t)(k0 + kk) * HW + bp + p4];
            float xs[4] = {g.x, g.y, g.z, g.w};
            #pragma unroll
            for (int i = 0; i < 4; ++i) {
                __hip_bfloat16 h = __float2bfloat16(xs[i]);
                float hf = __bfloat162float(h);
                __hip_bfloat16 lo = __float2bfloat16(xs[i] - hf);
                Xh[p4 + i][kk] = *(ushort_t*)&h;
                Xl[p4 + i][kk] = *(ushort_t*)&lo;
            }
        }
        __syncthreads();

        const short8v a1h = *(const short8v*)&W1h[arow + k0 + kg];
        const short8v a1l = *(const short8v*)&W1l[arow + k0 + kg];
        short8v a2h, a2l;
        if (NW == 2) {
            a2h = *(const short8v*)&W2h[arow + k0 + kg];
            a2l = *(const short8v*)&W2l[arow + k0 + kg];
        }
        #pragma unroll
        for (int pf = 0; pf < 4; ++pf) {
            const short8v bh = *(const short8v*)&Xh[pf * 16 + l15][kg];
            const short8v bl = *(const short8v*)&Xl[pf * 16 + l15][kg];
            acc1[pf] = __builtin_amdgcn_mfma_f32_16x16x32_bf16(a1h, bh, acc1[pf], 0, 0, 0);
            acc1[pf] = __builtin_amdgcn_mfma_f32_16x16x32_bf16(a1l, bh, acc1[pf], 0, 0, 0);
            acc1[pf] = __builtin_amdgcn_mfma_f32_16x16x32_bf16(a1h, bl, acc1[pf], 0, 0, 0);
            if (NW == 2) {
                acc2[pf] = __builtin_amdgcn_mfma_f32_16x16x32_bf16(a2h, bh, acc2[pf], 0, 0, 0);
                acc2[pf] = __builtin_amdgcn_mfma_f32_16x16x32_bf16(a2l, bh, acc2[pf], 0, 0, 0);
                acc2[pf] = __builtin_amdgcn_mfma_f32_16x16x32_bf16(a2h, bl, acc2[pf], 0, 0, 0);
            }
        }
    }

    // epilogue: fp32 stores, 16 lanes contiguous in p
    #pragma unroll
    for (int pf = 0; pf < 4; ++pf) {
        #pragma unroll
        for (int i = 0; i < 4; ++i) {
            const int e = estrip + (lane >> 4) * 4 + i;
            const int p = bp + pf * 16 + l15;
            C1[((size_t)b * D + e) * HW + p] = acc1[pf][i];
            if (NW == 2) C2[((size_t)b * D + e) * HW + p] = acc2[pf][i];
        }
    }
}

// ---------------- Scores + softmax (unchanged from passing round) -------------
__global__ __launch_bounds__(64) void scores_kernel(const float* __restrict__ q,
                                                    const float* __restrict__ knew,
                                                    const float* __restrict__ key_buffer,
                                                    float* __restrict__ attn,
                                                    float scale) {
    const int bx = blockIdx.x;           // b*L_*HS + l*HS + h
    const int b = bx / (L_ * HS);
    const int rem = bx % (L_ * HS);
    const int l = rem / HS;
    const int h = rem % HS;

    const int lane = threadIdx.x;
    const int p4 = lane & 15;
    const int dq = lane >> 4;

    const float* qbase = q + (size_t)b * QSTRIDE + h * WS_;
    const float* kbase = (l < 7)
        ? key_buffer + (size_t)(b * L_ + l + 1) * QSTRIDE + h * WS_
        : knew + (size_t)b * QSTRIDE + h * WS_;

    const float* kp = kbase + (size_t)(dq * 64) * HW + p4 * 4;
    const float* qp = qbase + (size_t)(dq * 64) * HW + p4 * 4;

    float4 s = {0.f, 0.f, 0.f, 0.f};
    #pragma unroll 8
    for (int d = 0; d < 64; ++d) {
        float4 kv = *(const float4*)kp; kp += HW;
        float4 qv = *(const float4*)qp; qp += HW;
        s.x += qv.x * kv.x; s.y += qv.y * kv.y;
        s.z += qv.z * kv.z; s.w += qv.w * kv.w;
    }
    #pragma unroll
    for (int off = 16; off <= 32; off <<= 1) {
        s.x += __shfl_xor(s.x, off);
        s.y += __shfl_xor(s.y, off);
        s.z += __shfl_xor(s.z, off);
        s.w += __shfl_xor(s.w, off);
    }
    s.x *= scale; s.y *= scale; s.z *= scale; s.w *= scale;

    float m = fmaxf(fmaxf(s.x, s.y), fmaxf(s.z, s.w));
    #pragma unroll
    for (int off = 1; off <= 8; off <<= 1) m = fmaxf(m, __shfl_xor(m, off));
    float4 e;
    e.x = __expf(s.x - m); e.y = __expf(s.y - m);
    e.z = __expf(s.z - m); e.w = __expf(s.w - m);
    float sum = e.x + e.y + e.z + e.w;
    #pragma unroll
    for (int off = 1; off <= 8; off <<= 1) sum += __shfl_xor(sum, off);
    float inv = 1.0f / sum;
    e.x *= inv; e.y *= inv; e.z *= inv; e.w *= inv;

    if (dq == 0) {
        *(float4*)&attn[(size_t)((b * L_ + l) * HS + h) * WS_ + p4 * 4] = e;
    }
}

// ---------------- PV + epilogue (unchanged from passing round) ----------------
__global__ __launch_bounds__(256) void pv_kernel(const float* __restrict__ attn,
                                                 const float* __restrict__ value_buffer,
                                                 const float* __restrict__ vnew,
                                                 const float* __restrict__ fm,
                                                 float* __restrict__ out) {
    const int bx = blockIdx.x;           // b*96 + h*2 + eh
    const int b = bx / 96;
    const int rem = bx % 96;
    const int h = rem >> 1;
    const int eh = rem & 1;

    const int tid = threadIdx.x;
    const int p4 = tid & 15;
    const int eg = tid >> 4;
    const int e0 = eh * 64 + eg * 4;

    float4 ar[8];
    #pragma unroll
    for (int l = 0; l < 8; ++l)
        ar[l] = *(const float4*)&attn[(size_t)((b * L_ + l) * HS + h) * WS_ + p4 * 4];

    const float* vb[8];
    #pragma unroll
    for (int l = 0; l < 7; ++l)
        vb[l] = value_buffer + (size_t)(b * L_ + l + 1) * VSTRIDE + h * WS_;
    vb[7] = vnew + (size_t)b * VSTRIDE + h * WS_;

    const float* fmb = fm + (size_t)b * VSTRIDE + h * WS_;
    float* outb = out + (size_t)b * VSTRIDE + h * WS_;

    #pragma unroll
    for (int i = 0; i < 4; ++i) {
        const int e = e0 + i;
        const size_t off = (size_t)e * HW + p4 * 4;
        float4 acc = {0.f, 0.f, 0.f, 0.f};
        #pragma unroll
        for (int l = 0; l < 8; ++l) {
            float4 v = *(const float4*)(vb[l] + off);
            acc.x += ar[l].x * v.x; acc.y += ar[l].y * v.y;
            acc.z += ar[l].z * v.z; acc.w += ar[l].w * v.w;
        }
        float4 f = *(const float4*)(fmb + off);
        f.x += acc.x; f.y += acc.y; f.z += acc.z; f.w += acc.w;
        *(float4*)(outb + off) = f;
    }
}

// ---------------- launcher ----------------------------------------------------
extern "C" void kernel_launch(void* const* d_in, const int* in_sizes, int n_in,
                              void* d_out, int out_size, void* d_ws, size_t ws_size,
                              hipStream_t stream) {
    const float* fc           = (const float*)d_in[0];
    const float* fm           = (const float*)d_in[1];
    const float* key_buffer   = (const float*)d_in[2];
    const float* value_buffer = (const float*)d_in[3];
    const float* Q            = (const float*)d_in[4];
    const float* K            = (const float*)d_in[5];
    const float* V            = (const float*)d_in[6];
    float* out = (float*)d_out;

    float* ws   = (float*)d_ws;
    float* q    = ws;                       // 6291456 f
    float* knew = ws + 6291456;             // 6291456 f
    float* vnew = ws + 12582912;            // 3145728 f
    float* attn = ws + 15728640;            // 196608 f
    ushort_t* wb = (ushort_t*)(ws + 15925248);
    ushort_t* WQh = wb;                     // 65536 each for Q/K, 16384 for V
    ushort_t* WQl = wb + 65536;
    ushort_t* WKh = wb + 131072;
    ushort_t* WKl = wb + 196608;
    ushort_t* WVh = wb + 262144;
    ushort_t* WVl = wb + 278528;

    const float scale = (float)(log(27648.0) / log(1000.0) / 16.0);

    prep_weights<<<640, 256, 0, stream>>>(Q, K, V, WQh, WQl, WKh, WKl, WVh, WVl);

    // q = fc@Q, knew = fc@K fused (fc read once); vnew = fm@V
    gemm_mfma<2, 256><<<dim3(HW / 64, 4, B_), 256, 0, stream>>>(
        fc, WQh, WQl, WKh, WKl, q, knew);
    gemm_mfma<1, 128><<<dim3(HW / 64, 2, B_), 256, 0, stream>>>(
        fm, WVh, WVl, nullptr, nullptr, vnew, nullptr);

    scores_kernel<<<B_ * L_ * HS, 64, 0, stream>>>(q, knew, key_buffer, attn, scale);
    pv_kernel<<<B_ * HS * 2, 256, 0, stream>>>(attn, value_buffer, vnew, fm, out);
}